// Round 21
// baseline (564.257 us; speedup 1.0000x reference)
//
#include <hip/hip_runtime.h>

#define B_ 128
#define T_ 100
#define D_ 256
#define H_ 512
#define L_ 40000
#define S_ 10

__device__ __forceinline__ float sigm_(float x){ return 1.f/(1.f + __expf(-x)); }
__device__ __forceinline__ float tanh_(float x){ return 1.f - 2.f/(__expf(2.f*x) + 1.f); }

typedef __attribute__((ext_vector_type(8))) short bf16x8;
typedef __attribute__((ext_vector_type(4))) float f32x4;

// RNE fp32 -> bf16 (as ushort)
__device__ __forceinline__ unsigned short bfhi_(float x){
  unsigned u = __float_as_uint(x);
  return (unsigned short)((u + 0x7FFFu + ((u >> 16) & 1u)) >> 16);
}
__device__ __forceinline__ float bf2f_(unsigned short h){
  return __uint_as_float(((unsigned)h) << 16);
}
// decode packed (hi | lo<<16) u32 -> fp32
__device__ __forceinline__ float decp_(unsigned u){
  return bf2f_((unsigned short)(u & 0xFFFFu)) + bf2f_((unsigned short)(u >> 16));
}

// ---------------- fused init: zero h_enc + flags + slot projections ----------------
__global__ void k_init(unsigned long long* __restrict__ h_enc, unsigned* __restrict__ flags,
                       const float* __restrict__ embed_s, const float* __restrict__ embed_q,
                       const float* __restrict__ w_s, const float* __restrict__ w_q,
                       float* __restrict__ es_proj, float* __restrict__ eq_proj){
  int bid = blockIdx.x, tid = threadIdx.x;
  if (bid < 256){ h_enc[bid*256 + tid] = 0ull; return; }         // 65536 u64 = 2*B*H/2
  if (bid == 256){ if (tid < 256) flags[tid] = 0u; return; }     // 256 u32
  int b2 = bid - 257;                                            // 0..39: projections
  int table = b2/20, rem = b2%20, s = rem/2, half = rem%2;
  int jo = half*256 + tid;
  const float* emb = (table ? embed_q : embed_s) + s*D_;
  const float* w   = (table ? w_q : w_s) + (size_t)(2*H_ + jo)*D_;   // o-gate rows
  float acc = 0.f;
  #pragma unroll 4
  for (int k=0;k<D_;++k) acc = fmaf(emb[k], w[k], acc);
  (table ? eq_proj : es_proj)[s*H_ + jo] = acc;
}

// ---------------- one-time bf16 hi/lo conversion of w_ih g/o rows (1024 x 256) ------
__global__ __launch_bounds__(256) void k_conv_w(
  const float* __restrict__ w_ih,
  unsigned short* __restrict__ Whi, unsigned short* __restrict__ Wlo)
{
  int g = blockIdx.x*256 + threadIdx.x;      // float4 group, 0..65535
  size_t row = (size_t)(g >> 6), k4 = (size_t)(g & 63)*4;
  const float* src = w_ih + (2*H_ + row)*D_ + k4;
  size_t off = row*D_ + k4;
  float4 v = *(const float4*)src;
  ushort4 hi, lo;
  hi.x = bfhi_(v.x); lo.x = bfhi_(v.x - bf2f_(hi.x));
  hi.y = bfhi_(v.y); lo.y = bfhi_(v.y - bf2f_(hi.y));
  hi.z = bfhi_(v.z); lo.z = bfhi_(v.z - bf2f_(hi.z));
  hi.w = bfhi_(v.w); lo.w = bfhi_(v.w - bf2f_(hi.w));
  *(ushort4*)(Whi + off) = hi;
  *(ushort4*)(Wlo + off) = lo;
}

// ---------------- phase 1 (MFMA, split-bf16; jt-tile x4) ----------------------------
// Round-21: each block handles 256 j (16 N-frags) instead of 64 -> A-gather traffic
// /4 (205->51MB), block count 3200->800. Same verified frag math (absmax 4.88e-4).
// acc[16] fully unrolled (compile-time indices, rule #20).
__global__ __launch_bounds__(256,2) void k_phase1(
  const int* __restrict__ batch_l, const float* __restrict__ embed_l,
  const unsigned short* __restrict__ Whi, const unsigned short* __restrict__ Wlo,
  const float* __restrict__ b_ih, const float* __restrict__ b_hh,
  const float* __restrict__ t_ld, const float* __restrict__ t_hd,
  const int* __restrict__ t_l, const int* __restrict__ t_h,
  const float* __restrict__ d_ld, const float* __restrict__ d_hd,
  const int* __restrict__ d_l, const int* __restrict__ d_h,
  const float* __restrict__ es_proj, const float* __restrict__ eq_proj,
  float* __restrict__ P)
{
  __shared__ int ridx[64];
  int mt = blockIdx.x, jg = blockIdx.y;                  // 200 x 4
  int t = mt >> 1, b0 = (mt & 1)*64;
  int tid = threadIdx.x;
  if (tid < 64) ridx[tid] = batch_l[(b0+tid)*T_ + t];
  __syncthreads();

  int lane = tid & 63, wv = tid >> 6;
  int ar = lane & 15, kb = lane >> 4;
  int mw = wv*16;
  f32x4 acc[16];
  #pragma unroll
  for (int nf=0;nf<16;++nf) acc[nf] = (f32x4){0.f,0.f,0.f,0.f};
  const float* arow_f = embed_l + (size_t)ridx[mw + ar]*D_ + kb*8;
  const size_t brow0 = (size_t)(jg*256 + ar)*D_ + kb*8;  // nf adds 16*D_
  #pragma unroll
  for (int kc=0; kc<8; ++kc){
    float4 f0 = *(const float4*)(arow_f + kc*32);
    float4 f1 = *(const float4*)(arow_f + kc*32 + 4);
    float vv[8] = {f0.x,f0.y,f0.z,f0.w,f1.x,f1.y,f1.z,f1.w};
    bf16x8 a_hi, a_lo;
    #pragma unroll
    for (int i=0;i<8;++i){
      unsigned short h = bfhi_(vv[i]);
      a_hi[i] = (short)h;
      a_lo[i] = (short)bfhi_(vv[i] - bf2f_(h));
    }
    #pragma unroll
    for (int nf=0; nf<16; ++nf){
      bf16x8 b_hi = *(const bf16x8*)(Whi + brow0 + (size_t)nf*16*D_ + kc*32);
      bf16x8 b_lo = *(const bf16x8*)(Wlo + brow0 + (size_t)nf*16*D_ + kc*32);
      acc[nf] = __builtin_amdgcn_mfma_f32_16x16x32_bf16(a_hi, b_hi, acc[nf], 0, 0, 0);
      acc[nf] = __builtin_amdgcn_mfma_f32_16x16x32_bf16(a_hi, b_lo, acc[nf], 0, 0, 0);
      acc[nf] = __builtin_amdgcn_mfma_f32_16x16x32_bf16(a_lo, b_hi, acc[nf], 0, 0, 0);
    }
  }

  // ---- epilogue: bias + (j>=512 <=> jg>=2) slot interp; D: col=l&15, row=(l>>4)*4+r
  float bias[16];
  #pragma unroll
  for (int nf=0; nf<16; ++nf){
    int j = jg*256 + nf*16 + ar;
    bias[nf] = b_ih[2*H_ + j] + b_hh[2*H_ + j];
  }
  #pragma unroll
  for (int r=0; r<4; ++r){
    int b = b0 + mw + kb*4 + r;
    float dldv=0.f, dhdv=0.f, tldv=0.f, thdv=0.f;
    int dlv=0, dhv=0, tlv=0, thv=0;
    if (jg >= 2){
      int bt = b*T_ + t;
      dldv=d_ld[bt]; dhdv=d_hd[bt]; tldv=t_ld[bt]; thdv=t_hd[bt];
      dlv=d_l[bt]; dhv=d_h[bt]; tlv=t_l[bt]; thv=t_h[bt];
    }
    #pragma unroll
    for (int nf=0; nf<16; ++nf){
      int j = jg*256 + nf*16 + ar;
      float v = acc[nf][r] + bias[nf];
      if (jg >= 2){
        int jo = j - 512;
        v += dhdv*es_proj[dlv*H_+jo] + dldv*es_proj[dhv*H_+jo]
           + thdv*eq_proj[tlv*H_+jo] + tldv*eq_proj[thv*H_+jo];
      }
      P[((size_t)t*B_ + b)*1024 + j] = v;
    }
  }
}

// ---------------- recurrence: persistent, 256 WGs x 256 thr = 16 bg x 16 js ---------
// Round-21 = r20 MFMA recurrence (341us proven) + LDS bank-conflict fix: hb pair
// stride 20 -> 18 words. Writes: 8x ds_write_b64 at 72*tid bytes (8B aligned; banks
// 18*tid mod 32 hit all 16 banks, only tid/tid+16 alias = free 2-way — was 8-way on
// b128 at stride 20). Reads: the four 16-lane groups land on bank offsets 0/8/16/24
// (delta 72 words = 8 mod 32) -> conflict-free. Protocol/math byte-identical to r20.
__global__ __launch_bounds__(256,1) void k_rec(
  const float* __restrict__ w_hh, const float* __restrict__ P,
  unsigned long long* __restrict__ h_enc, unsigned* __restrict__ flags)
{
  extern __shared__ char smc[];
  unsigned short* Whi = (unsigned short*)smc;            // [64][528] bf16
  unsigned short* Wlo = Whi + 64*528;                    // [64][528]
  unsigned* hb = (unsigned*)(Wlo + 64*528);              // [256 pairs][18 words]
  int bid = blockIdx.x;
  int bg = bid & 15, js = bid >> 4;
  int tid = threadIdx.x;
  int lane = tid & 63, wv = tid >> 6;
  const int gb0 = bg*8;
  unsigned* bgflags = flags + bg*16;

  // ---- stage W once: LDS row r = w*16+rr; rr<8 -> g(js*32+w*8+rr), rr>=8 -> o(...)
  {
    int r = tid >> 2;                  // 0..63
    int c0 = (tid & 3)*128;
    int rr = r & 15;
    int jrow = js*32 + (r>>4)*8 + (rr & 7);
    const float* src = w_hh + (size_t)(((rr<8)?2:3)*H_ + jrow)*H_ + c0;
    unsigned short* dhi = Whi + r*528 + c0;
    unsigned short* dlo = Wlo + r*528 + c0;
    #pragma unroll 4
    for (int i=0;i<32;++i){
      float4 v = *(const float4*)(src + i*4);
      ushort4 hi, lo;
      hi.x=bfhi_(v.x); lo.x=bfhi_(v.x-bf2f_(hi.x));
      hi.y=bfhi_(v.y); lo.y=bfhi_(v.y-bf2f_(hi.y));
      hi.z=bfhi_(v.z); lo.z=bfhi_(v.z-bf2f_(hi.z));
      hi.w=bfhi_(v.w); lo.w=bfhi_(v.w-bf2f_(hi.w));
      *(ushort4*)(dhi + i*4) = hi;
      *(ushort4*)(dlo + i*4) = lo;
    }
  }

  const bool live = (lane < 32) && ((lane & 15) < 8);
  int bb = lane & 15;                               // batch (live lanes)
  int j0l = js*32 + wv*8 + (lane>>4)*4;             // 4 consecutive j (lane<32)
  float pgv[4] = {0,0,0,0}, pov[4] = {0,0,0,0};
  if (live){
    size_t prow = (size_t)(gb0 + bb)*1024;
    float4 g4 = *(const float4*)&P[prow + j0l];
    float4 o4 = *(const float4*)&P[prow + 512 + j0l];
    pgv[0]=g4.x; pgv[1]=g4.y; pgv[2]=g4.z; pgv[3]=g4.w;
    pov[0]=o4.x; pov[1]=o4.y; pov[2]=o4.z; pov[3]=o4.w;
  }
  const int arow_off = (wv*16 + (lane & 15))*528 + (lane>>4)*8;
  const int hcol = lane & 7;
  const int hp0 = (lane>>4)*4;                      // pair offset of this group

  for (int t=0; t<T_; ++t){
    int par = t & 1;
    if (t > 0 && tid < 16){                         // r11 poll: one 64B line
      unsigned* f = bgflags + tid;
      int guard = 0;
      while (__hip_atomic_load(f, __ATOMIC_RELAXED, __HIP_MEMORY_SCOPE_AGENT) < (unsigned)t){
        __builtin_amdgcn_s_sleep(4);
        if (++guard > (1<<22)) break;               // safety bail
      }
    }
    __syncthreads();                                // t=0: W staged; t>0: prev reads done

    // ---- stage h: thread tid owns u64 index tid (j-pair 2tid,2tid+1) for b=0..7
    const unsigned long long* hsrc =
      h_enc + (size_t)par*(B_*H_/2) + (size_t)gb0*256 + tid;
    unsigned long long v[8];
    #pragma unroll
    for (int b=0;b<8;++b)
      v[b] = __hip_atomic_load(&hsrc[(size_t)b*256], __ATOMIC_RELAXED, __HIP_MEMORY_SCOPE_AGENT);
    {
      unsigned* r0 = hb + tid*18;                   // row 2tid: words 0..7, row 2tid+1: 8..15
      *(uint2*)(r0+ 0) = make_uint2((unsigned)v[0],(unsigned)v[1]);
      *(uint2*)(r0+ 2) = make_uint2((unsigned)v[2],(unsigned)v[3]);
      *(uint2*)(r0+ 4) = make_uint2((unsigned)v[4],(unsigned)v[5]);
      *(uint2*)(r0+ 6) = make_uint2((unsigned)v[6],(unsigned)v[7]);
      *(uint2*)(r0+ 8) = make_uint2((unsigned)(v[0]>>32),(unsigned)(v[1]>>32));
      *(uint2*)(r0+10) = make_uint2((unsigned)(v[2]>>32),(unsigned)(v[3]>>32));
      *(uint2*)(r0+12) = make_uint2((unsigned)(v[4]>>32),(unsigned)(v[5]>>32));
      *(uint2*)(r0+14) = make_uint2((unsigned)(v[6]>>32),(unsigned)(v[7]>>32));
    }
    __syncthreads();

    // ---- MFMA: 16 k-steps x 3 split products; hb addr = 18*pair + (k&1)*8 + col
    f32x4 ac0 = {0,0,0,0}, ac1 = {0,0,0,0}, ac2 = {0,0,0,0};
    #pragma unroll
    for (int kc=0; kc<16; ++kc){
      bf16x8 bh, bl;
      #pragma unroll
      for (int e=0;e<8;++e){
        unsigned u = hb[(kc*16 + hp0 + (e>>1))*18 + (e&1)*8 + hcol];
        bh[e] = (short)(u & 0xFFFFu);
        bl[e] = (short)(u >> 16);
      }
      bf16x8 ah = *(const bf16x8*)(Whi + arow_off + kc*32);
      bf16x8 al = *(const bf16x8*)(Wlo + arow_off + kc*32);
      ac0 = __builtin_amdgcn_mfma_f32_16x16x32_bf16(ah, bh, ac0, 0, 0, 0);
      ac1 = __builtin_amdgcn_mfma_f32_16x16x32_bf16(ah, bl, ac1, 0, 0, 0);
      ac2 = __builtin_amdgcn_mfma_f32_16x16x32_bf16(al, bh, ac2, 0, 0, 0);
    }
    float accv[4], oov[4];
    #pragma unroll
    for (int r=0;r<4;++r) accv[r] = ac0[r] + ac1[r] + ac2[r];
    #pragma unroll
    for (int r=0;r<4;++r) oov[r] = __shfl_xor(accv[r], 32, 64);  // lanes<32 get oo

    if (live){
      float h[4];
      #pragma unroll
      for (int r=0;r<4;++r){
        float gg = accv[r] + pgv[r];
        float oo = oov[r]  + pov[r];
        h[r] = sigm_(oo)*tanh_(tanh_(gg));
      }
      unsigned short p0h=bfhi_(h[0]), p0l=bfhi_(h[0]-bf2f_(p0h));
      unsigned short p1h=bfhi_(h[1]), p1l=bfhi_(h[1]-bf2f_(p1h));
      unsigned short p2h=bfhi_(h[2]), p2l=bfhi_(h[2]-bf2f_(p2h));
      unsigned short p3h=bfhi_(h[3]), p3l=bfhi_(h[3]-bf2f_(p3h));
      unsigned long long u0 = (unsigned long long)p0h | ((unsigned long long)p0l<<16)
                            | ((unsigned long long)p1h<<32) | ((unsigned long long)p1l<<48);
      unsigned long long u1 = (unsigned long long)p2h | ((unsigned long long)p2l<<16)
                            | ((unsigned long long)p3h<<32) | ((unsigned long long)p3l<<48);
      unsigned long long* dst =
        h_enc + (size_t)(1-par)*(B_*H_/2) + (size_t)(gb0 + bb)*256 + (j0l>>1);
      __hip_atomic_store(dst,   u0, __ATOMIC_RELAXED, __HIP_MEMORY_SCOPE_AGENT);
      __hip_atomic_store(dst+1, u1, __ATOMIC_RELAXED, __HIP_MEMORY_SCOPE_AGENT);
      if (t+1 < T_){                                // prefetch next-step P
        size_t prow = ((size_t)(t+1)*B_ + gb0 + bb)*1024;
        float4 g4 = *(const float4*)&P[prow + j0l];
        float4 o4 = *(const float4*)&P[prow + 512 + j0l];
        pgv[0]=g4.x; pgv[1]=g4.y; pgv[2]=g4.z; pgv[3]=g4.w;
        pov[0]=o4.x; pov[1]=o4.y; pov[2]=o4.z; pov[3]=o4.w;
      }
    }
    __syncthreads();   // per-wave vmcnt(0): h stores visible before flag
    if (t+1 < T_ && tid == 0)
      __hip_atomic_store(bgflags + js, (unsigned)(t+1),
                         __ATOMIC_RELAXED, __HIP_MEMORY_SCOPE_AGENT);
  }
}

// ---------------- classifier: out = hT @ w_out.T + b_out (hT = packed h_enc par-0) --
__global__ __launch_bounds__(256) void k_cls(
  const unsigned long long* __restrict__ h_enc, const float* __restrict__ w_out,
  const float* __restrict__ b_out, float* __restrict__ out)
{
  __shared__ float wt[32*68];     // [k][l] k-major
  __shared__ float htl[32*132];   // [k][b]
  int l0 = blockIdx.x * 64;       // 625 blocks
  int tid = threadIdx.x;
  int lq = tid >> 4, bq = tid & 15;
  float acc[4][8] = {};
  for (int kc=0; kc<16; ++kc){
    int k0 = kc*32;
    __syncthreads();
    #pragma unroll
    for (int it=0; it<2; ++it){   // w_out tile via float4
      int f = it*256 + tid;       // 0..511
      int l = f >> 3, k4 = (f & 7)*4;
      float4 v = *(const float4*)&w_out[(size_t)(l0+l)*H_ + k0 + k4];
      wt[(k4+0)*68 + l] = v.x; wt[(k4+1)*68 + l] = v.y;
      wt[(k4+2)*68 + l] = v.z; wt[(k4+3)*68 + l] = v.w;
    }
    #pragma unroll
    for (int it=0; it<4; ++it){   // hT tile: 2 u64 = 4 k-cols, decode hi+lo
      int f = it*256 + tid;       // 0..1023
      int b = f >> 3, k4 = (f & 7)*4;
      uint4 v = *(const uint4*)&h_enc[(size_t)b*256 + ((k0 + k4) >> 1)];
      htl[(k4+0)*132 + b] = decp_(v.x);
      htl[(k4+1)*132 + b] = decp_(v.y);
      htl[(k4+2)*132 + b] = decp_(v.z);
      htl[(k4+3)*132 + b] = decp_(v.w);
    }
    __syncthreads();
    #pragma unroll 4
    for (int k=0;k<32;++k){
      float4 w4 = *(const float4*)&wt[k*68 + lq*4];
      float4 h0 = *(const float4*)&htl[k*132 + bq*8];
      float4 h1 = *(const float4*)&htl[k*132 + bq*8 + 4];
      float wv[4] = {w4.x,w4.y,w4.z,w4.w};
      float hv[8] = {h0.x,h0.y,h0.z,h0.w,h1.x,h1.y,h1.z,h1.w};
      #pragma unroll
      for (int m=0;m<4;++m)
        #pragma unroll
        for (int i=0;i<8;++i) acc[m][i] = fmaf(wv[m], hv[i], acc[m][i]);
    }
  }
  int l = l0 + lq*4;
  float4 bo = *(const float4*)&b_out[l];
  #pragma unroll
  for (int i=0;i<8;++i){
    int b = bq*8 + i;
    float4 o4;
    o4.x = acc[0][i] + bo.x; o4.y = acc[1][i] + bo.y;
    o4.z = acc[2][i] + bo.z; o4.w = acc[3][i] + bo.w;
    *(float4*)&out[(size_t)b*L_ + l] = o4;
  }
}

extern "C" void kernel_launch(void* const* d_in, const int* in_sizes, int n_in,
                              void* d_out, int out_size, void* d_ws, size_t ws_size,
                              hipStream_t stream) {
  const int*   batch_l = (const int*)  d_in[0];
  const float* t_ld    = (const float*)d_in[1];
  const float* t_hd    = (const float*)d_in[2];
  const int*   t_l     = (const int*)  d_in[3];
  const int*   t_h     = (const int*)  d_in[4];
  const float* d_ld    = (const float*)d_in[5];
  const float* d_hd    = (const float*)d_in[6];
  const int*   d_l     = (const int*)  d_in[7];
  const int*   d_h     = (const int*)  d_in[8];
  const float* embed_l = (const float*)d_in[9];
  const float* embed_s = (const float*)d_in[10];
  const float* embed_q = (const float*)d_in[11];
  const float* w_ih    = (const float*)d_in[12];
  const float* w_hh    = (const float*)d_in[13];
  const float* w_s     = (const float*)d_in[14];
  const float* w_q     = (const float*)d_in[15];
  const float* b_ih    = (const float*)d_in[16];
  const float* b_hh    = (const float*)d_in[17];
  const float* w_out   = (const float*)d_in[18];
  const float* b_out   = (const float*)d_in[19];
  float* out = (float*)d_out;

  // workspace layout (float offsets; h_enc u64 at even-float offset -> 16B aligned)
  float* ws = (float*)d_ws;
  const size_t P_off   = 0;                         // 13107200 f
  const size_t h_off   = 13107200;                  // 131072 f = 65536 u64 (2 parities)
  const size_t es_off  = h_off + 131072;            // 5120 f
  const size_t eq_off  = es_off + 5120;             // 5120 f
  const size_t flg_off = eq_off + 5120;             // 256 u32
  const size_t whi_off = flg_off + 256;             // 1024*256 ushort = 131072 f
  const size_t wlo_off = whi_off + 131072;
  const size_t need_full = (wlo_off + 131072)*4 + 64;
  if (ws_size < need_full) return;

  float* P        = ws + P_off;
  unsigned long long* h_enc = (unsigned long long*)(ws + h_off);
  float* es_proj  = ws + es_off;
  float* eq_proj  = ws + eq_off;
  unsigned* flags = (unsigned*)(ws + flg_off);
  unsigned short* Whi = (unsigned short*)(ws + whi_off);
  unsigned short* Wlo = (unsigned short*)(ws + wlo_off);

  hipFuncSetAttribute(reinterpret_cast<const void*>(k_rec),
                      hipFuncAttributeMaxDynamicSharedMemorySize, 153600);

  k_init<<<297, 256, 0, stream>>>(h_enc, flags, embed_s, embed_q, w_s, w_q,
                                  es_proj, eq_proj);
  k_conv_w<<<256, 256, 0, stream>>>(w_ih, Whi, Wlo);
  k_phase1<<<dim3(200,4), 256, 0, stream>>>(batch_l, embed_l, Whi, Wlo,
      b_ih, b_hh, t_ld, t_hd, t_l, t_h, d_ld, d_hd, d_l, d_h, es_proj, eq_proj, P);
  k_rec<<<256, 256, 153600, stream>>>(w_hh, P, h_enc, flags);
  k_cls<<<625, 256, 0, stream>>>(h_enc, w_out, b_out, out);
}